// Round 15
// baseline (711.839 us; speedup 1.0000x reference)
//
#include <hip/hip_runtime.h>
#include <cstdint>

#define D 128
#define BKT_SHIFT 8
#define BKT_CAP 5120
#define EDGES_PER_BLOCK 4096
#define NREP 8

typedef __attribute__((ext_vector_type(4))) float floatx4;
typedef __attribute__((ext_vector_type(4))) _Float16 half4;
typedef __attribute__((ext_vector_type(8))) _Float16 half8;

__device__ __forceinline__ float elu_f(float x) {
    return x > 0.0f ? x : __expf(x) - 1.0f;
}

// ================= bucketed CSR build (bump-allocated, no prepass) =================
__global__ void init_cursor_kernel(int* __restrict__ gcursor, int NB) {
    int t = blockIdx.x * 256 + threadIdx.x;
    if (t < NB) gcursor[t] = t * BKT_CAP;
}

__global__ __launch_bounds__(256) void bucket_scatter_kernel(
    const int* __restrict__ src, const int* __restrict__ dst,
    int* __restrict__ gcursor, int2* __restrict__ staging, int E, int NB) {
    __shared__ int lcnt[512];
    __shared__ int lbase[512];
    int t = threadIdx.x;
    lcnt[t] = 0; lcnt[t + 256] = 0;
    __syncthreads();
    int base = blockIdx.x * EDGES_PER_BLOCK;
    int s_[16], d_[16], r_[16];
#pragma unroll
    for (int i = 0; i < 16; ++i) {
        int idx = base + i * 256 + t;
        if (idx < E) {
            s_[i] = src[idx];
            d_[i] = dst[idx];
            r_[i] = atomicAdd(&lcnt[d_[i] >> BKT_SHIFT], 1);
        }
    }
    __syncthreads();
    for (int b = t; b < NB; b += 256) {
        int c = lcnt[b];
        if (c) lbase[b] = atomicAdd(&gcursor[b], c);
    }
    __syncthreads();
#pragma unroll
    for (int i = 0; i < 16; ++i) {
        int idx = base + i * 256 + t;
        if (idx < E) {
            int bkt = d_[i] >> BKT_SHIFT;
            staging[lbase[bkt] + r_[i]] = make_int2(s_[i], d_[i]);
        }
    }
}

__global__ __launch_bounds__(256) void bucket_build_kernel(
    const int2* __restrict__ staging, const int* __restrict__ gcursor,
    int* __restrict__ rowstart, int* __restrict__ rowend,
    int* __restrict__ col, int N) {
    __shared__ int hcnt[256];
    __shared__ int hoff[256];
    int t = threadIdx.x;
    int node0 = blockIdx.x << BKT_SHIFT;
    int off0 = blockIdx.x * BKT_CAP;
    int off1 = gcursor[blockIdx.x];
    hcnt[t] = 0;
    __syncthreads();
    for (int i = off0 + t; i < off1; i += 256)
        atomicAdd(&hcnt[staging[i].y - node0], 1);
    __syncthreads();
    int deg = hcnt[t];
    hoff[t] = deg;
    __syncthreads();
    for (int off = 1; off < 256; off <<= 1) {
        int u = (t >= off) ? hoff[t - off] : 0;
        __syncthreads();
        hoff[t] += u;
        __syncthreads();
    }
    int myoff = (t == 0) ? 0 : hoff[t - 1];
    __syncthreads();
    hoff[t] = myoff;
    hcnt[t] = 0;
    if (node0 + t < N) {
        rowstart[node0 + t] = off0 + myoff;
        rowend[node0 + t] = off0 + myoff + deg;
    }
    __syncthreads();
    for (int i = off0 + t; i < off1; i += 256) {
        int2 p = staging[i];
        int dl = p.y - node0;
        int pos = off0 + hoff[dl] + atomicAdd(&hcnt[dl], 1);
        col[pos] = p.x;
    }
}

// ---------------- fp32 -> fp16 convert (x before layer 0) ----------------
__global__ void to_half_kernel(const float* __restrict__ in, _Float16* __restrict__ outp, int n4) {
    int i = blockIdx.x * 256 + threadIdx.x;
    if (i >= n4) return;
    float4 v = ((const float4*)in)[i];
    half4 h = {(_Float16)v.x, (_Float16)v.y, (_Float16)v.z, (_Float16)v.w};
    ((half4*)outp)[i] = h;
}

// ---------------- W prep: fragment-permuted fp16 hi/lo layout ----------------
__global__ void wprep_kernel(const float* __restrict__ W1, const float* __restrict__ W2,
                             _Float16* __restrict__ Wph, _Float16* __restrict__ Wpl,
                             int total) {
    int idx = blockIdx.x * 256 + threadIdx.x;
    if (idx >= total) return;
    int mat = idx >> 14;
    int rem = idx & 16383;
    int tile = rem >> 9;
    int lane = (rem >> 3) & 63;
    int j = rem & 7;
    int ks = tile >> 3, nt = tile & 7;
    int n = nt * 16 + (lane & 15);
    int k = ks * 32 + (lane >> 4) * 8 + j;
    int l = mat >> 1;
    const float* W = (mat & 1) ? W2 : W1;
    float v = W[(size_t)l * D * D + k * D + n];
    _Float16 h = (_Float16)v;
    _Float16 lo = (_Float16)(v - (float)h);
    Wph[idx] = h;
    Wpl[idx] = lo;
}

// ---------------- MFMA GEMM (fp16 A, fp16 hi/lo W, 2 terms), 32x128 tile ----------------
// 8 blocks/CU, grid ~3125 (>=12 blocks/CU) keeps slots full for the whole dispatch.
// GATHER: A = h16[node] + sum_neighbors h16[j] (single-stream 8-deep batches, 2 rows/group).
// else: A = elu(Z16*scale+shift), scale/shift from 8-replica colsum_in (BN fused).
template <bool GATHER, bool ELU_OUT, bool STATS>
__global__ __launch_bounds__(256, 8) void gemm_mfma(
    const _Float16* __restrict__ Hh,
    const int* __restrict__ rowstart, const int* __restrict__ rowend,
    const int* __restrict__ col,
    const _Float16* __restrict__ Z,
    const _Float16* __restrict__ Wph, const _Float16* __restrict__ Wpl,
    const float* __restrict__ bias,
    const float* __restrict__ colsum_in, const float* __restrict__ gamma,
    const float* __restrict__ beta,
    _Float16* __restrict__ outp16, float* __restrict__ colsum_out, int N) {
    __shared__ _Float16 sA[32 * 136];
    __shared__ float bnsum[2 * D];
    __shared__ float s_sc[D];
    __shared__ float s_sh[D];
    const int tid = threadIdx.x;
    const int row0 = blockIdx.x * 32;

    if (STATS && tid < 2 * D) bnsum[tid] = 0.f;

    if (GATHER) {
        const int rg = tid >> 4;     // 0..15 row groups (2 rows each)
        const int q = tid & 15;      // half8 lane (8 channels)
        const half8* hh8 = (const half8*)Hh;
#pragma unroll
        for (int i = 0; i < 2; ++i) {
            int r = rg * 2 + i;
            int node = row0 + r;
            float a0 = 0.f, a1 = 0.f, a2 = 0.f, a3 = 0.f;
            float a4 = 0.f, a5 = 0.f, a6 = 0.f, a7 = 0.f;
            if (node < N) {
                half8 sf = hh8[(size_t)node * 16 + q];
                a0 = (float)sf[0]; a1 = (float)sf[1]; a2 = (float)sf[2]; a3 = (float)sf[3];
                a4 = (float)sf[4]; a5 = (float)sf[5]; a6 = (float)sf[6]; a7 = (float)sf[7];
                int e0 = rowstart[node], e1 = rowend[node];
                int e = e0;
                for (; e + 7 < e1; e += 8) {
                    int j0 = col[e],     j1 = col[e + 1], j2 = col[e + 2], j3 = col[e + 3];
                    int j4 = col[e + 4], j5 = col[e + 5], j6 = col[e + 6], j7 = col[e + 7];
                    half8 v0 = hh8[(size_t)j0 * 16 + q];
                    half8 v1 = hh8[(size_t)j1 * 16 + q];
                    half8 v2 = hh8[(size_t)j2 * 16 + q];
                    half8 v3 = hh8[(size_t)j3 * 16 + q];
                    half8 v4 = hh8[(size_t)j4 * 16 + q];
                    half8 v5 = hh8[(size_t)j5 * 16 + q];
                    half8 v6 = hh8[(size_t)j6 * 16 + q];
                    half8 v7 = hh8[(size_t)j7 * 16 + q];
                    a0 += ((float)v0[0] + (float)v1[0] + (float)v2[0] + (float)v3[0])
                        + ((float)v4[0] + (float)v5[0] + (float)v6[0] + (float)v7[0]);
                    a1 += ((float)v0[1] + (float)v1[1] + (float)v2[1] + (float)v3[1])
                        + ((float)v4[1] + (float)v5[1] + (float)v6[1] + (float)v7[1]);
                    a2 += ((float)v0[2] + (float)v1[2] + (float)v2[2] + (float)v3[2])
                        + ((float)v4[2] + (float)v5[2] + (float)v6[2] + (float)v7[2]);
                    a3 += ((float)v0[3] + (float)v1[3] + (float)v2[3] + (float)v3[3])
                        + ((float)v4[3] + (float)v5[3] + (float)v6[3] + (float)v7[3]);
                    a4 += ((float)v0[4] + (float)v1[4] + (float)v2[4] + (float)v3[4])
                        + ((float)v4[4] + (float)v5[4] + (float)v6[4] + (float)v7[4]);
                    a5 += ((float)v0[5] + (float)v1[5] + (float)v2[5] + (float)v3[5])
                        + ((float)v4[5] + (float)v5[5] + (float)v6[5] + (float)v7[5]);
                    a6 += ((float)v0[6] + (float)v1[6] + (float)v2[6] + (float)v3[6])
                        + ((float)v4[6] + (float)v5[6] + (float)v6[6] + (float)v7[6]);
                    a7 += ((float)v0[7] + (float)v1[7] + (float)v2[7] + (float)v3[7])
                        + ((float)v4[7] + (float)v5[7] + (float)v6[7] + (float)v7[7]);
                }
                for (; e < e1; ++e) {
                    half8 v = hh8[(size_t)col[e] * 16 + q];
                    a0 += (float)v[0]; a1 += (float)v[1]; a2 += (float)v[2]; a3 += (float)v[3];
                    a4 += (float)v[4]; a5 += (float)v[5]; a6 += (float)v[6]; a7 += (float)v[7];
                }
            }
            half8 hv = {(_Float16)a0, (_Float16)a1, (_Float16)a2, (_Float16)a3,
                        (_Float16)a4, (_Float16)a5, (_Float16)a6, (_Float16)a7};
            *(half8*)&sA[r * 136 + q * 8] = hv;
        }
    } else {
        if (tid < D) {
            float s = 0.f, s2 = 0.f;
#pragma unroll
            for (int rp = 0; rp < NREP; ++rp) {
                s  += colsum_in[rp * 2 * D + tid];
                s2 += colsum_in[rp * 2 * D + D + tid];
            }
            float invN = 1.0f / (float)N;
            float mu = s * invN;
            float var = s2 * invN - mu * mu;
            float rs = rsqrtf(var + 1e-5f);
            float sc = gamma[tid] * rs;
            s_sc[tid] = sc;
            s_sh[tid] = beta[tid] - mu * sc;
        }
        __syncthreads();
#pragma unroll
        for (int it = 0; it < 2; ++it) {
            int idx = tid + it * 256;
            int r = idx >> 4;           // 0..31
            int q8 = (idx & 15) * 8;    // channel offset
            int gr = row0 + r;
            half8 z = {};
            if (gr < N) z = *(const half8*)&Z[(size_t)gr * D + q8];
            float v0 = elu_f((float)z[0] * s_sc[q8 + 0] + s_sh[q8 + 0]);
            float v1 = elu_f((float)z[1] * s_sc[q8 + 1] + s_sh[q8 + 1]);
            float v2 = elu_f((float)z[2] * s_sc[q8 + 2] + s_sh[q8 + 2]);
            float v3 = elu_f((float)z[3] * s_sc[q8 + 3] + s_sh[q8 + 3]);
            float v4 = elu_f((float)z[4] * s_sc[q8 + 4] + s_sh[q8 + 4]);
            float v5 = elu_f((float)z[5] * s_sc[q8 + 5] + s_sh[q8 + 5]);
            float v6 = elu_f((float)z[6] * s_sc[q8 + 6] + s_sh[q8 + 6]);
            float v7 = elu_f((float)z[7] * s_sc[q8 + 7] + s_sh[q8 + 7]);
            half8 hv = {(_Float16)v0, (_Float16)v1, (_Float16)v2, (_Float16)v3,
                        (_Float16)v4, (_Float16)v5, (_Float16)v6, (_Float16)v7};
            *(half8*)&sA[r * 136 + q8] = hv;
        }
    }
    __syncthreads();

    const int wave = tid >> 6, lane = tid & 63;
    const int wm = wave >> 1, wn = wave & 1;   // wm: 16-row half, wn: 64-col half
    const int l15 = lane & 15, quad = lane >> 4;
    const half8* bph = (const half8*)Wph;
    const half8* bpl = (const half8*)Wpl;

    floatx4 acc[4];
#pragma unroll
    for (int nt = 0; nt < 4; ++nt)
        acc[nt] = (floatx4){0.f, 0.f, 0.f, 0.f};

#pragma unroll
    for (int ks = 0; ks < 4; ++ks) {
        const int kf = ks * 32 + quad * 8;
        half8 ah = *(const half8*)&sA[(wm * 16 + l15) * 136 + kf];
        // stream B per-nt to keep live registers low
#pragma unroll
        for (int nt = 0; nt < 4; ++nt) {
            int tIdx = (ks * 8 + wn * 4 + nt) * 64 + lane;
            half8 bh = bph[tIdx];
            half8 bl = bpl[tIdx];
            acc[nt] = __builtin_amdgcn_mfma_f32_16x16x32_f16(ah, bh, acc[nt], 0, 0, 0);
            acc[nt] = __builtin_amdgcn_mfma_f32_16x16x32_f16(ah, bl, acc[nt], 0, 0, 0);
        }
    }

#pragma unroll
    for (int nt = 0; nt < 4; ++nt) {
        int c = wn * 64 + nt * 16 + l15;
        float b = bias[c];
        float s = 0.f, s2 = 0.f;
#pragma unroll
        for (int r = 0; r < 4; ++r) {
            int gm = row0 + wm * 16 + quad * 4 + r;
            float v = acc[nt][r] + b;
            if (ELU_OUT) v = elu_f(v);
            if (gm < N) {
                outp16[(size_t)gm * D + c] = (_Float16)v;
                if (STATS) { s += v; s2 += v * v; }
            }
        }
        if (STATS) {
            atomicAdd(&bnsum[c], s);
            atomicAdd(&bnsum[D + c], s2);
        }
    }
    if (STATS) {
        __syncthreads();
        float* rep = colsum_out + (size_t)(blockIdx.x & (NREP - 1)) * 2 * D;
        if (tid < D) {
            atomicAdd(&rep[tid], bnsum[tid]);
            atomicAdd(&rep[D + tid], bnsum[D + tid]);
        }
    }
}

// ---------------- global mean pool (fp16 input) ----------------
__global__ __launch_bounds__(128) void pool_kernel(
    const _Float16* __restrict__ h, const int* __restrict__ batch,
    float* __restrict__ pooled, float* __restrict__ cnt, int N) {
    int c = threadIdx.x;
    int r0 = blockIdx.x * 256;
    if (r0 >= N) return;
    int rend = r0 + 256; if (rend > N) rend = N;
    int cur = batch[r0];
    float acc = 0.f;
    float cacc = 0.f;
    for (int r = r0; r < rend; ++r) {
        int b = batch[r];
        if (b != cur) {
            atomicAdd(&pooled[(size_t)cur * D + c], acc);
            if (c == 0) atomicAdd(&cnt[cur], cacc);
            acc = 0.f; cacc = 0.f; cur = b;
        }
        acc += (float)h[(size_t)r * D + c];
        cacc += 1.f;
    }
    atomicAdd(&pooled[(size_t)cur * D + c], acc);
    if (c == 0) atomicAdd(&cnt[cur], cacc);
}

__global__ void final_linear_kernel(const float* __restrict__ pooled,
                                    const float* __restrict__ cnt,
                                    const float* __restrict__ linW,
                                    const float* __restrict__ linb,
                                    float* __restrict__ out, int G) {
    int t = blockIdx.x * blockDim.x + threadIdx.x;
    if (t >= G * 2) return;
    int g = t >> 1, o = t & 1;
    float inv = 1.0f / fmaxf(cnt[g], 1.0f);
    float s = linb[o];
    for (int c = 0; c < D; ++c)
        s += pooled[(size_t)g * D + c] * inv * linW[c * 2 + o];
    out[t] = s;
}

extern "C" void kernel_launch(void* const* d_in, const int* in_sizes, int n_in,
                              void* d_out, int out_size, void* d_ws, size_t ws_size,
                              hipStream_t stream) {
    const float* x      = (const float*)d_in[0];
    const int*  eidx    = (const int*)d_in[1];
    const int*  batch   = (const int*)d_in[2];
    const float* W1     = (const float*)d_in[3];
    const float* b1     = (const float*)d_in[4];
    const float* gamma  = (const float*)d_in[5];
    const float* beta   = (const float*)d_in[6];
    const float* W2     = (const float*)d_in[7];
    const float* b2     = (const float*)d_in[8];
    const float* linW   = (const float*)d_in[9];
    const float* linb   = (const float*)d_in[10];
    float* out = (float*)d_out;

    const int N = in_sizes[0] / D;
    const int E = in_sizes[1] / 2;
    const int L = in_sizes[3] / (D * D);
    const int G = out_size / 2;
    const int* esrc = eidx;
    const int* edst = eidx + E;
    const int NB = (N + 255) >> 8;

    size_t off = 0;
    auto carve = [&](size_t bytes) -> void* {
        void* p = (char*)d_ws + off;
        off += (bytes + 255) & ~(size_t)255;
        return p;
    };
    const size_t ND = (size_t)N * D;
    const int WTOT = 2 * L * D * D;
    _Float16* z16   = (_Float16*)carve(ND * 2);      // aliased as CSR staging (12.8MB <= 25.6MB)
    _Float16* hhalf = (_Float16*)carve(ND * 2);
    _Float16* Wph = (_Float16*)carve((size_t)WTOT * 2);
    _Float16* Wpl = (_Float16*)carve((size_t)WTOT * 2);
    int* rowstart = (int*)carve((size_t)N * 4);
    int* rowend   = (int*)carve((size_t)N * 4);
    int* col      = (int*)carve((size_t)NB * BKT_CAP * 4);
    float* colsum4 = (float*)carve((size_t)4 * NREP * 2 * D * 4);
    int* gcursor  = (int*)carve(512 * 4);
    float* pooled = (float*)carve((size_t)G * D * 4); // contiguous with cnt: one memset
    float* cnt    = (float*)carve((size_t)G * 4);
    int2* staging = (int2*)z16;
    (void)ws_size; (void)n_in;

    hipMemsetAsync(colsum4, 0, (size_t)4 * NREP * 2 * D * 4, stream);
    hipMemsetAsync(pooled, 0, (size_t)G * D * 4 + (size_t)G * 4, stream);

    const int EB = (E + EDGES_PER_BLOCK - 1) / EDGES_PER_BLOCK;
    init_cursor_kernel<<<(NB + 255) / 256, 256, 0, stream>>>(gcursor, NB);
    bucket_scatter_kernel<<<EB, 256, 0, stream>>>(esrc, edst, gcursor, staging, E, NB);
    bucket_build_kernel<<<NB, 256, 0, stream>>>(staging, gcursor, rowstart, rowend, col, N);
    wprep_kernel<<<(WTOT + 255) / 256, 256, 0, stream>>>(W1, W2, Wph, Wpl, WTOT);
    to_half_kernel<<<(int)((ND / 4 + 255) / 256), 256, 0, stream>>>(x, hhalf, (int)(ND / 4));

    const int gemm_grid = (N + 31) / 32;
    for (int l = 0; l < L; ++l) {
        float* colsum = colsum4 + (size_t)l * NREP * 2 * D;
        gemm_mfma<true, false, true><<<gemm_grid, 256, 0, stream>>>(
            hhalf, rowstart, rowend, col, nullptr,
            Wph + (size_t)(l * 2) * D * D, Wpl + (size_t)(l * 2) * D * D,
            b1 + (size_t)l * D, nullptr, nullptr, nullptr, z16, colsum, N);
        gemm_mfma<false, true, false><<<gemm_grid, 256, 0, stream>>>(
            nullptr, nullptr, nullptr, nullptr, z16,
            Wph + (size_t)(l * 2 + 1) * D * D, Wpl + (size_t)(l * 2 + 1) * D * D,
            b2 + (size_t)l * D, colsum, gamma + (size_t)l * D, beta + (size_t)l * D,
            hhalf, nullptr, N);
    }

    pool_kernel<<<(N + 255) / 256, 128, 0, stream>>>(hhalf, batch, pooled, cnt, N);
    final_linear_kernel<<<(G * 2 + 255) / 256, 256, 0, stream>>>(pooled, cnt, linW, linb, out, G);
}

// Round 16
// 667.044 us; speedup vs baseline: 1.0672x; 1.0672x over previous
//
#include <hip/hip_runtime.h>
#include <cstdint>

#define D 128
#define BKT_SHIFT 8
#define BKT_CAP 5120
#define EDGES_PER_BLOCK 4096
#define NREP 8

typedef __attribute__((ext_vector_type(4))) float floatx4;
typedef __attribute__((ext_vector_type(4))) _Float16 half4;
typedef __attribute__((ext_vector_type(8))) _Float16 half8;

__device__ __forceinline__ float elu_f(float x) {
    return x > 0.0f ? x : __expf(x) - 1.0f;
}

// ================= bucketed CSR build (bump-allocated, no prepass) =================
__global__ void init_cursor_kernel(int* __restrict__ gcursor, int NB) {
    int t = blockIdx.x * 256 + threadIdx.x;
    if (t < NB) gcursor[t] = t * BKT_CAP;
}

__global__ __launch_bounds__(256) void bucket_scatter_kernel(
    const int* __restrict__ src, const int* __restrict__ dst,
    int* __restrict__ gcursor, int2* __restrict__ staging, int E, int NB) {
    __shared__ int lcnt[512];
    __shared__ int lbase[512];
    int t = threadIdx.x;
    lcnt[t] = 0; lcnt[t + 256] = 0;
    __syncthreads();
    int base = blockIdx.x * EDGES_PER_BLOCK;
    int s_[16], d_[16], r_[16];
#pragma unroll
    for (int i = 0; i < 16; ++i) {
        int idx = base + i * 256 + t;
        if (idx < E) {
            s_[i] = src[idx];
            d_[i] = dst[idx];
            r_[i] = atomicAdd(&lcnt[d_[i] >> BKT_SHIFT], 1);
        }
    }
    __syncthreads();
    for (int b = t; b < NB; b += 256) {
        int c = lcnt[b];
        if (c) lbase[b] = atomicAdd(&gcursor[b], c);
    }
    __syncthreads();
#pragma unroll
    for (int i = 0; i < 16; ++i) {
        int idx = base + i * 256 + t;
        if (idx < E) {
            int bkt = d_[i] >> BKT_SHIFT;
            staging[lbase[bkt] + r_[i]] = make_int2(s_[i], d_[i]);
        }
    }
}

__global__ __launch_bounds__(256) void bucket_build_kernel(
    const int2* __restrict__ staging, const int* __restrict__ gcursor,
    int* __restrict__ rowstart, int* __restrict__ rowend,
    int* __restrict__ col, int N) {
    __shared__ int hcnt[256];
    __shared__ int hoff[256];
    int t = threadIdx.x;
    int node0 = blockIdx.x << BKT_SHIFT;
    int off0 = blockIdx.x * BKT_CAP;
    int off1 = gcursor[blockIdx.x];
    hcnt[t] = 0;
    __syncthreads();
    for (int i = off0 + t; i < off1; i += 256)
        atomicAdd(&hcnt[staging[i].y - node0], 1);
    __syncthreads();
    int deg = hcnt[t];
    hoff[t] = deg;
    __syncthreads();
    for (int off = 1; off < 256; off <<= 1) {
        int u = (t >= off) ? hoff[t - off] : 0;
        __syncthreads();
        hoff[t] += u;
        __syncthreads();
    }
    int myoff = (t == 0) ? 0 : hoff[t - 1];
    __syncthreads();
    hoff[t] = myoff;
    hcnt[t] = 0;
    if (node0 + t < N) {
        rowstart[node0 + t] = off0 + myoff;
        rowend[node0 + t] = off0 + myoff + deg;
    }
    __syncthreads();
    for (int i = off0 + t; i < off1; i += 256) {
        int2 p = staging[i];
        int dl = p.y - node0;
        int pos = off0 + hoff[dl] + atomicAdd(&hcnt[dl], 1);
        col[pos] = p.x;
    }
}

// ---------------- fp32 -> fp16 convert (x before layer 0) ----------------
__global__ void to_half_kernel(const float* __restrict__ in, _Float16* __restrict__ outp, int n4) {
    int i = blockIdx.x * 256 + threadIdx.x;
    if (i >= n4) return;
    float4 v = ((const float4*)in)[i];
    half4 h = {(_Float16)v.x, (_Float16)v.y, (_Float16)v.z, (_Float16)v.w};
    ((half4*)outp)[i] = h;
}

// ---------------- W prep: fragment-permuted fp16 hi/lo layout ----------------
__global__ void wprep_kernel(const float* __restrict__ W1, const float* __restrict__ W2,
                             _Float16* __restrict__ Wph, _Float16* __restrict__ Wpl,
                             int total) {
    int idx = blockIdx.x * 256 + threadIdx.x;
    if (idx >= total) return;
    int mat = idx >> 14;
    int rem = idx & 16383;
    int tile = rem >> 9;
    int lane = (rem >> 3) & 63;
    int j = rem & 7;
    int ks = tile >> 3, nt = tile & 7;
    int n = nt * 16 + (lane & 15);
    int k = ks * 32 + (lane >> 4) * 8 + j;
    int l = mat >> 1;
    const float* W = (mat & 1) ? W2 : W1;
    float v = W[(size_t)l * D * D + k * D + n];
    _Float16 h = (_Float16)v;
    _Float16 lo = (_Float16)(v - (float)h);
    Wph[idx] = h;
    Wpl[idx] = lo;
}

// ---------------- MFMA GEMM (fp16 A, fp16 hi/lo W, 2 terms), 64x128 tile ----------------
// 8 blocks/CU: VGPR<=64 (measured 32), LDS 18432/instance. B-fragments streamed per-nt.
// GATHER: A = h16[node] + sum_neighbors h16[j] (single-stream 8-deep batches).
// else: A = elu(Z16*scale+shift), scale/shift from 8-replica colsum_in (BN fused).
template <bool GATHER, bool ELU_OUT, bool STATS>
__global__ __launch_bounds__(256, 8) void gemm_mfma(
    const _Float16* __restrict__ Hh,
    const int* __restrict__ rowstart, const int* __restrict__ rowend,
    const int* __restrict__ col,
    const _Float16* __restrict__ Z,
    const _Float16* __restrict__ Wph, const _Float16* __restrict__ Wpl,
    const float* __restrict__ bias,
    const float* __restrict__ colsum_in, const float* __restrict__ gamma,
    const float* __restrict__ beta,
    _Float16* __restrict__ outp16, float* __restrict__ colsum_out, int N) {
    __shared__ _Float16 sA[64 * 136];
    __shared__ float bnsum[2 * D];
    __shared__ float s_sc[D];
    __shared__ float s_sh[D];
    const int tid = threadIdx.x;
    const int row0 = blockIdx.x * 64;

    if (STATS && tid < 2 * D) bnsum[tid] = 0.f;

    if (GATHER) {
        const int rg = tid >> 4;     // 0..15 row groups (4 rows each)
        const int q = tid & 15;      // half8 lane (8 channels)
        const half8* hh8 = (const half8*)Hh;
#pragma unroll
        for (int i = 0; i < 4; ++i) {
            int r = rg * 4 + i;
            int node = row0 + r;
            float a0 = 0.f, a1 = 0.f, a2 = 0.f, a3 = 0.f;
            float a4 = 0.f, a5 = 0.f, a6 = 0.f, a7 = 0.f;
            if (node < N) {
                half8 sf = hh8[(size_t)node * 16 + q];
                a0 = (float)sf[0]; a1 = (float)sf[1]; a2 = (float)sf[2]; a3 = (float)sf[3];
                a4 = (float)sf[4]; a5 = (float)sf[5]; a6 = (float)sf[6]; a7 = (float)sf[7];
                int e0 = rowstart[node], e1 = rowend[node];
                int e = e0;
                for (; e + 7 < e1; e += 8) {
                    int j0 = col[e],     j1 = col[e + 1], j2 = col[e + 2], j3 = col[e + 3];
                    int j4 = col[e + 4], j5 = col[e + 5], j6 = col[e + 6], j7 = col[e + 7];
                    half8 v0 = hh8[(size_t)j0 * 16 + q];
                    half8 v1 = hh8[(size_t)j1 * 16 + q];
                    half8 v2 = hh8[(size_t)j2 * 16 + q];
                    half8 v3 = hh8[(size_t)j3 * 16 + q];
                    half8 v4 = hh8[(size_t)j4 * 16 + q];
                    half8 v5 = hh8[(size_t)j5 * 16 + q];
                    half8 v6 = hh8[(size_t)j6 * 16 + q];
                    half8 v7 = hh8[(size_t)j7 * 16 + q];
                    a0 += ((float)v0[0] + (float)v1[0] + (float)v2[0] + (float)v3[0])
                        + ((float)v4[0] + (float)v5[0] + (float)v6[0] + (float)v7[0]);
                    a1 += ((float)v0[1] + (float)v1[1] + (float)v2[1] + (float)v3[1])
                        + ((float)v4[1] + (float)v5[1] + (float)v6[1] + (float)v7[1]);
                    a2 += ((float)v0[2] + (float)v1[2] + (float)v2[2] + (float)v3[2])
                        + ((float)v4[2] + (float)v5[2] + (float)v6[2] + (float)v7[2]);
                    a3 += ((float)v0[3] + (float)v1[3] + (float)v2[3] + (float)v3[3])
                        + ((float)v4[3] + (float)v5[3] + (float)v6[3] + (float)v7[3]);
                    a4 += ((float)v0[4] + (float)v1[4] + (float)v2[4] + (float)v3[4])
                        + ((float)v4[4] + (float)v5[4] + (float)v6[4] + (float)v7[4]);
                    a5 += ((float)v0[5] + (float)v1[5] + (float)v2[5] + (float)v3[5])
                        + ((float)v4[5] + (float)v5[5] + (float)v6[5] + (float)v7[5]);
                    a6 += ((float)v0[6] + (float)v1[6] + (float)v2[6] + (float)v3[6])
                        + ((float)v4[6] + (float)v5[6] + (float)v6[6] + (float)v7[6]);
                    a7 += ((float)v0[7] + (float)v1[7] + (float)v2[7] + (float)v3[7])
                        + ((float)v4[7] + (float)v5[7] + (float)v6[7] + (float)v7[7]);
                }
                for (; e < e1; ++e) {
                    half8 v = hh8[(size_t)col[e] * 16 + q];
                    a0 += (float)v[0]; a1 += (float)v[1]; a2 += (float)v[2]; a3 += (float)v[3];
                    a4 += (float)v[4]; a5 += (float)v[5]; a6 += (float)v[6]; a7 += (float)v[7];
                }
            }
            half8 hv = {(_Float16)a0, (_Float16)a1, (_Float16)a2, (_Float16)a3,
                        (_Float16)a4, (_Float16)a5, (_Float16)a6, (_Float16)a7};
            *(half8*)&sA[r * 136 + q * 8] = hv;
        }
    } else {
        if (tid < D) {
            float s = 0.f, s2 = 0.f;
#pragma unroll
            for (int rp = 0; rp < NREP; ++rp) {
                s  += colsum_in[rp * 2 * D + tid];
                s2 += colsum_in[rp * 2 * D + D + tid];
            }
            float invN = 1.0f / (float)N;
            float mu = s * invN;
            float var = s2 * invN - mu * mu;
            float rs = rsqrtf(var + 1e-5f);
            float sc = gamma[tid] * rs;
            s_sc[tid] = sc;
            s_sh[tid] = beta[tid] - mu * sc;
        }
        __syncthreads();
#pragma unroll
        for (int it = 0; it < 4; ++it) {
            int idx = tid + it * 256;
            int r = idx >> 4;           // 0..63
            int q8 = (idx & 15) * 8;    // channel offset
            int gr = row0 + r;
            half8 z = {};
            if (gr < N) z = *(const half8*)&Z[(size_t)gr * D + q8];
            float v0 = elu_f((float)z[0] * s_sc[q8 + 0] + s_sh[q8 + 0]);
            float v1 = elu_f((float)z[1] * s_sc[q8 + 1] + s_sh[q8 + 1]);
            float v2 = elu_f((float)z[2] * s_sc[q8 + 2] + s_sh[q8 + 2]);
            float v3 = elu_f((float)z[3] * s_sc[q8 + 3] + s_sh[q8 + 3]);
            float v4 = elu_f((float)z[4] * s_sc[q8 + 4] + s_sh[q8 + 4]);
            float v5 = elu_f((float)z[5] * s_sc[q8 + 5] + s_sh[q8 + 5]);
            float v6 = elu_f((float)z[6] * s_sc[q8 + 6] + s_sh[q8 + 6]);
            float v7 = elu_f((float)z[7] * s_sc[q8 + 7] + s_sh[q8 + 7]);
            half8 hv = {(_Float16)v0, (_Float16)v1, (_Float16)v2, (_Float16)v3,
                        (_Float16)v4, (_Float16)v5, (_Float16)v6, (_Float16)v7};
            *(half8*)&sA[r * 136 + q8] = hv;
        }
    }
    __syncthreads();

    const int wave = tid >> 6, lane = tid & 63;
    const int wm = wave >> 1, wn = wave & 1;
    const int l15 = lane & 15, quad = lane >> 4;
    const half8* bph = (const half8*)Wph;
    const half8* bpl = (const half8*)Wpl;

    floatx4 acc[2][4];
#pragma unroll
    for (int mt = 0; mt < 2; ++mt)
#pragma unroll
        for (int nt = 0; nt < 4; ++nt)
            acc[mt][nt] = (floatx4){0.f, 0.f, 0.f, 0.f};

#pragma unroll
    for (int ks = 0; ks < 4; ++ks) {
        const int kf = ks * 32 + quad * 8;
        half8 ah[2];
#pragma unroll
        for (int mt = 0; mt < 2; ++mt)
            ah[mt] = *(const half8*)&sA[(wm * 32 + mt * 16 + l15) * 136 + kf];
        // stream B per-nt to keep live registers low (8 blocks/CU target)
#pragma unroll
        for (int nt = 0; nt < 4; ++nt) {
            int tIdx = (ks * 8 + wn * 4 + nt) * 64 + lane;
            half8 bh = bph[tIdx];
            half8 bl = bpl[tIdx];
            acc[0][nt] = __builtin_amdgcn_mfma_f32_16x16x32_f16(ah[0], bh, acc[0][nt], 0, 0, 0);
            acc[1][nt] = __builtin_amdgcn_mfma_f32_16x16x32_f16(ah[1], bh, acc[1][nt], 0, 0, 0);
            acc[0][nt] = __builtin_amdgcn_mfma_f32_16x16x32_f16(ah[0], bl, acc[0][nt], 0, 0, 0);
            acc[1][nt] = __builtin_amdgcn_mfma_f32_16x16x32_f16(ah[1], bl, acc[1][nt], 0, 0, 0);
        }
    }

#pragma unroll
    for (int nt = 0; nt < 4; ++nt) {
        int c = wn * 64 + nt * 16 + l15;
        float b = bias[c];
        float s = 0.f, s2 = 0.f;
#pragma unroll
        for (int mt = 0; mt < 2; ++mt) {
#pragma unroll
            for (int r = 0; r < 4; ++r) {
                int gm = row0 + wm * 32 + mt * 16 + quad * 4 + r;
                float v = acc[mt][nt][r] + b;
                if (ELU_OUT) v = elu_f(v);
                if (gm < N) {
                    outp16[(size_t)gm * D + c] = (_Float16)v;
                    if (STATS) { s += v; s2 += v * v; }
                }
            }
        }
        if (STATS) {
            atomicAdd(&bnsum[c], s);
            atomicAdd(&bnsum[D + c], s2);
        }
    }
    if (STATS) {
        __syncthreads();
        float* rep = colsum_out + (size_t)(blockIdx.x & (NREP - 1)) * 2 * D;
        if (tid < D) {
            atomicAdd(&rep[tid], bnsum[tid]);
            atomicAdd(&rep[D + tid], bnsum[D + tid]);
        }
    }
}

// ---------------- global mean pool (fp16 input) ----------------
__global__ __launch_bounds__(128) void pool_kernel(
    const _Float16* __restrict__ h, const int* __restrict__ batch,
    float* __restrict__ pooled, float* __restrict__ cnt, int N) {
    int c = threadIdx.x;
    int r0 = blockIdx.x * 256;
    if (r0 >= N) return;
    int rend = r0 + 256; if (rend > N) rend = N;
    int cur = batch[r0];
    float acc = 0.f;
    float cacc = 0.f;
    for (int r = r0; r < rend; ++r) {
        int b = batch[r];
        if (b != cur) {
            atomicAdd(&pooled[(size_t)cur * D + c], acc);
            if (c == 0) atomicAdd(&cnt[cur], cacc);
            acc = 0.f; cacc = 0.f; cur = b;
        }
        acc += (float)h[(size_t)r * D + c];
        cacc += 1.f;
    }
    atomicAdd(&pooled[(size_t)cur * D + c], acc);
    if (c == 0) atomicAdd(&cnt[cur], cacc);
}

__global__ void final_linear_kernel(const float* __restrict__ pooled,
                                    const float* __restrict__ cnt,
                                    const float* __restrict__ linW,
                                    const float* __restrict__ linb,
                                    float* __restrict__ out, int G) {
    int t = blockIdx.x * blockDim.x + threadIdx.x;
    if (t >= G * 2) return;
    int g = t >> 1, o = t & 1;
    float inv = 1.0f / fmaxf(cnt[g], 1.0f);
    float s = linb[o];
    for (int c = 0; c < D; ++c)
        s += pooled[(size_t)g * D + c] * inv * linW[c * 2 + o];
    out[t] = s;
}

extern "C" void kernel_launch(void* const* d_in, const int* in_sizes, int n_in,
                              void* d_out, int out_size, void* d_ws, size_t ws_size,
                              hipStream_t stream) {
    const float* x      = (const float*)d_in[0];
    const int*  eidx    = (const int*)d_in[1];
    const int*  batch   = (const int*)d_in[2];
    const float* W1     = (const float*)d_in[3];
    const float* b1     = (const float*)d_in[4];
    const float* gamma  = (const float*)d_in[5];
    const float* beta   = (const float*)d_in[6];
    const float* W2     = (const float*)d_in[7];
    const float* b2     = (const float*)d_in[8];
    const float* linW   = (const float*)d_in[9];
    const float* linb   = (const float*)d_in[10];
    float* out = (float*)d_out;

    const int N = in_sizes[0] / D;
    const int E = in_sizes[1] / 2;
    const int L = in_sizes[3] / (D * D);
    const int G = out_size / 2;
    const int* esrc = eidx;
    const int* edst = eidx + E;
    const int NB = (N + 255) >> 8;

    size_t off = 0;
    auto carve = [&](size_t bytes) -> void* {
        void* p = (char*)d_ws + off;
        off += (bytes + 255) & ~(size_t)255;
        return p;
    };
    const size_t ND = (size_t)N * D;
    const int WTOT = 2 * L * D * D;
    _Float16* z16   = (_Float16*)carve(ND * 2);      // aliased as CSR staging (12.8MB <= 25.6MB)
    _Float16* hhalf = (_Float16*)carve(ND * 2);
    _Float16* Wph = (_Float16*)carve((size_t)WTOT * 2);
    _Float16* Wpl = (_Float16*)carve((size_t)WTOT * 2);
    int* rowstart = (int*)carve((size_t)N * 4);
    int* rowend   = (int*)carve((size_t)N * 4);
    int* col      = (int*)carve((size_t)NB * BKT_CAP * 4);
    float* colsum4 = (float*)carve((size_t)4 * NREP * 2 * D * 4);
    int* gcursor  = (int*)carve(512 * 4);
    float* pooled = (float*)carve((size_t)G * D * 4); // contiguous with cnt: one memset
    float* cnt    = (float*)carve((size_t)G * 4);
    int2* staging = (int2*)z16;
    (void)ws_size; (void)n_in;

    hipMemsetAsync(colsum4, 0, (size_t)4 * NREP * 2 * D * 4, stream);
    hipMemsetAsync(pooled, 0, (size_t)G * D * 4 + (size_t)G * 4, stream);

    const int EB = (E + EDGES_PER_BLOCK - 1) / EDGES_PER_BLOCK;
    init_cursor_kernel<<<(NB + 255) / 256, 256, 0, stream>>>(gcursor, NB);
    bucket_scatter_kernel<<<EB, 256, 0, stream>>>(esrc, edst, gcursor, staging, E, NB);
    bucket_build_kernel<<<NB, 256, 0, stream>>>(staging, gcursor, rowstart, rowend, col, N);
    wprep_kernel<<<(WTOT + 255) / 256, 256, 0, stream>>>(W1, W2, Wph, Wpl, WTOT);
    to_half_kernel<<<(int)((ND / 4 + 255) / 256), 256, 0, stream>>>(x, hhalf, (int)(ND / 4));

    const int gemm_grid = (N + 63) / 64;
    for (int l = 0; l < L; ++l) {
        float* colsum = colsum4 + (size_t)l * NREP * 2 * D;
        gemm_mfma<true, false, true><<<gemm_grid, 256, 0, stream>>>(
            hhalf, rowstart, rowend, col, nullptr,
            Wph + (size_t)(l * 2) * D * D, Wpl + (size_t)(l * 2) * D * D,
            b1 + (size_t)l * D, nullptr, nullptr, nullptr, z16, colsum, N);
        gemm_mfma<false, true, false><<<gemm_grid, 256, 0, stream>>>(
            nullptr, nullptr, nullptr, nullptr, z16,
            Wph + (size_t)(l * 2 + 1) * D * D, Wpl + (size_t)(l * 2 + 1) * D * D,
            b2 + (size_t)l * D, colsum, gamma + (size_t)l * D, beta + (size_t)l * D,
            hhalf, nullptr, N);
    }

    pool_kernel<<<(N + 255) / 256, 128, 0, stream>>>(hhalf, batch, pooled, cnt, N);
    final_linear_kernel<<<(G * 2 + 255) / 256, 256, 0, stream>>>(pooled, cnt, linW, linb, out, G);
}